// Round 10
// baseline (903.291 us; speedup 1.0000x reference)
//
#include <hip/hip_runtime.h>

#define Bn 128
#define Wn 64

typedef _Float16 h2 __attribute__((ext_vector_type(2)));

// ---- device state ----
__device__ unsigned g_f1[256];                  // hcp-half ready, value t+1
__device__ unsigned g_f2[2][256];               // gate-half ready (per posting wave)
__device__ unsigned g_post1[256][2][256];       // hcp half-K sums (f32 bits)
__device__ unsigned g_post2[256][2][1024];      // gate half-K sums
__device__ unsigned g_ep16[Bn * Wn * 128];      // eproj f16 pairs [b][w][128]
__device__ float4 g_encfc[Bn * Wn];             // fc_w[:, :256] @ enc
__device__ float4 g_encfcf[Bn * Wn];            // fcf_w[:, 256:] @ enc
__device__ uint4 g_ws[2 * 24576];               // packed f16 stream [p][chunk 24][t 1024]

__device__ __forceinline__ float ftanh(float x) {
  float p = __builtin_exp2f(x * 2.885390081777927f);
  return 1.0f - 2.0f * __builtin_amdgcn_rcpf(p + 1.0f);
}
__device__ __forceinline__ float fsigm(float x) {
  float p = __builtin_exp2f(-x * 1.4426950408889634f);
  return __builtin_amdgcn_rcpf(1.0f + p);
}
__device__ __forceinline__ float dot4(float4 a, float4 b) {
  return a.x * b.x + a.y * b.y + a.z * b.z + a.w * b.w;
}
__device__ __forceinline__ float fd2(unsigned w, unsigned h, float acc) {
  h2 a = __builtin_bit_cast(h2, w), b = __builtin_bit_cast(h2, h);
#if __has_builtin(__builtin_amdgcn_fdot2)
  return __builtin_amdgcn_fdot2(a, b, acc, false);
#else
  return acc + (float)a.x * (float)b.x + (float)a.y * (float)b.y;
#endif
}
__device__ __forceinline__ float fd2x4u(uint4 w, uint4 h, float acc) {
  acc = fd2(w.x, h.x, acc);
  acc = fd2(w.y, h.y, acc);
  acc = fd2(w.z, h.z, acc);
  acc = fd2(w.w, h.w, acc);
  return acc;
}
__device__ __forceinline__ unsigned pk(float a, float b) {
  h2 h = {(_Float16)a, (_Float16)b};
  return __builtin_bit_cast(unsigned, h);
}
__device__ __forceinline__ void ast(unsigned* p, unsigned v) {
  __hip_atomic_store(p, v, __ATOMIC_RELAXED, __HIP_MEMORY_SCOPE_AGENT);
}
__device__ __forceinline__ unsigned ald(unsigned* p) {
  return __hip_atomic_load(p, __ATOMIC_RELAXED, __HIP_MEMORY_SCOPE_AGENT);
}

// ---------------- reset flags ----------------
__global__ void reset_kernel() {
  int t = threadIdx.x;
  if (t < 256) { g_f1[t] = 0u; g_f2[0][t] = 0u; g_f2[1][t] = 0u; }
}

// ---------------- pack weights: g_ws[p][c][t] per decoder mapping ----------------
__global__ __launch_bounds__(256) void pack_kernel(const float* __restrict__ w1,
                                                   const float* __restrict__ w_hh) {
  int idx = blockIdx.x * 256 + threadIdx.x;  // 49152
  int p = idx / 24576, lin = idx % 24576;
  int c = lin >> 10, t = lin & 1023;
  int kb = t >> 9;
  const float* src;
  if (c < 8) {
    int e = (t & 511) >> 1;
    int kq = 2 * (t & 1) + kb;
    int ih = 8 * (8 * kq + c);  // half index in [h_p|c_p] 256-vector
    int col = (ih < 128) ? (128 * p + ih) : (256 + 128 * p + (ih - 128));
    src = w1 + (size_t)e * 768 + col;
  } else {
    int r = (t & 511) + ((c < 16) ? 0 : 512);
    int cc = (c < 16) ? (c - 8) : (c - 16);
    src = w_hh + (size_t)r * 256 + 128 * p + 64 * kb + 8 * cc;
  }
  uint4 o;
  o.x = pk(src[0], src[1]); o.y = pk(src[2], src[3]);
  o.z = pk(src[4], src[5]); o.w = pk(src[6], src[7]);
  g_ws[idx] = o;
}

// ---------------- eproj: b1 + W1e @ enc -> f16 pairs ----------------
__global__ __launch_bounds__(256) void eproj_kernel(const float* __restrict__ enc,
                                                    const float* __restrict__ w1,
                                                    const float* __restrict__ b1) {
  __shared__ __align__(16) float4 encs[16][64];
  __shared__ float accs[16][256];
  const int m0 = blockIdx.x * 16;
  const int tid = threadIdx.x;
  const float4* eg = (const float4*)(enc + (size_t)m0 * 256);
#pragma unroll
  for (int i = 0; i < 4; i++) {
    int idx = tid + 256 * i;
    encs[idx >> 6][idx & 63] = eg[idx];
  }
  __syncthreads();
  const int e = tid;
  float acc[16];
#pragma unroll
  for (int i = 0; i < 16; i++) acc[i] = 0.f;
  const float4* wrow = (const float4*)(w1 + e * 768 + 512);
  for (int k4 = 0; k4 < 64; k4++) {
    float4 wv = wrow[k4];
#pragma unroll
    for (int i = 0; i < 16; i++) acc[i] += dot4(wv, encs[i][k4]);
  }
  float bb = b1[e];
#pragma unroll
  for (int i = 0; i < 16; i++) accs[i][e] = acc[i] + bb;
  __syncthreads();
#pragma unroll
  for (int r = 0; r < 8; r++) {
    int idx = r * 256 + tid;
    int i = idx >> 7, jp = idx & 127;
    g_ep16[(size_t)(m0 + i) * 128 + jp] = pk(accs[i][2 * jp], accs[i][2 * jp + 1]);
  }
}

// ---------------- ENCFC / ENCFCF precompute ----------------
__global__ __launch_bounds__(256) void encfc_kernel(const float* __restrict__ enc,
                                                    const float* __restrict__ fc_w,
                                                    const float* __restrict__ fcf_w) {
  __shared__ __align__(16) float4 encs[16][64];
  const int m0 = blockIdx.x * 16;
  const int tid = threadIdx.x;
  const float4* eg = (const float4*)(enc + (size_t)m0 * 256);
#pragma unroll
  for (int i = 0; i < 4; i++) {
    int idx = tid + 256 * i;
    encs[idx >> 6][idx & 63] = eg[idx];
  }
  __syncthreads();
  if (tid < 128) {
    const int r = tid >> 3, o = tid & 7;
    const float* wr = (o < 4) ? (fc_w + o * 260) : (fcf_w + (o - 4) * 512 + 256);
    const float4* w4 = (const float4*)wr;
    float a = 0.f;
#pragma unroll 8
    for (int k = 0; k < 64; k++) a += dot4(w4[k], encs[r][k]);
    if (o < 4) ((float*)&g_encfc[m0 + r])[o] = a;
    else ((float*)&g_encfcf[m0 + r])[o - 4] = a;
  }
}

// -------- decoder: k-split pair, 1024 thr (16 waves/CU), overlapped exchange --------
__global__ __launch_bounds__(1024, 1) void decoder_kernel(
    const float* __restrict__ yhist, const float* __restrict__ w2,
    const float* __restrict__ w_ih, const float* __restrict__ b_ih,
    const float* __restrict__ b_hh,
    const float* __restrict__ fc_w, const float* __restrict__ fc_b,
    const float* __restrict__ fcf_w, const float* __restrict__ fcf_b,
    float* __restrict__ out) {
  __shared__ __align__(16) uint4 ep4u[2048];      // eproj [u4 32][w 64]      32 KB
  __shared__ __align__(16) float4 wihl[1024];     // w_ih rows                16 KB
  __shared__ float ag2[2048];                     // gate partials [kb][row]   8 KB
  __shared__ float gpar_in[1024];                 // partner gate partials     4 KB
  __shared__ float att_par[1024];                 // [slice 16][w 64]          4 KB
  __shared__ float hcp2[512];                     // hcp partials [kb][e]      2 KB
  __shared__ float hcp_in[256];
  __shared__ __align__(16) unsigned st32[256];    // state: h[0..256),c halves
  __shared__ float hn_l[256];
  __shared__ __align__(16) float4 yh_l[64];
  __shared__ float w2_l[256];
  __shared__ float fcy_l[16];
  __shared__ float fcb_l[4];
  __shared__ uint4 pad_force1wg[704];             // pad LDS > 80 KB -> 1 WG/CU

  const int g = blockIdx.x, t = threadIdx.x;
  const int b = g & 127, p = g >> 7, other = g ^ 128;
  const int l = t & 63, wid = t >> 6;
  const int kb = t >> 9, r = t & 511, e = (t & 511) >> 1;

  const uint4* ws = g_ws + (size_t)p * 24576 + t;   // chunk c at + c*1024
  const uint4* stu = (const uint4*)st32;
  const float4 efc = g_encfc[b * 64 + l];
  float4 bs4;
  if (t < 256) {
    bs4.x = b_ih[t] + b_hh[t];
    bs4.y = b_ih[256 + t] + b_hh[256 + t];
    bs4.z = b_ih[512 + t] + b_hh[512 + t];
    bs4.w = b_ih[768 + t] + b_hh[768 + t];
  }

  // ---- LDS init ----
  if (t < 256) { st32[t] = 0u; w2_l[t] = w2[t]; }
  wihl[t] = ((const float4*)w_ih)[t];
  if (t < 64) yh_l[t] = ((const float4*)yhist)[b * 64 + t];
  if (t < 16) fcy_l[t] = fc_w[(t >> 2) * 260 + 256 + (t & 3)];
  if (t < 4) fcb_l[t] = fc_b[t];
#pragma unroll
  for (int i = 0; i < 2; i++) {
    int lin = t + 1024 * i;                       // 2048 uint4
    int u = lin >> 6, w = lin & 63;
    ep4u[u * 64 + w] = *(const uint4*)&g_ep16[((size_t)(b * 64 + w)) * 128 + 4 * u];
  }
  pad_force1wg[t & 511] = ep4u[0];  // touch pad (keeps allocation)
  float c_reg = 0.f;
  float attw = 0.f;
  __syncthreads();

  for (int tt = 0; tt < Wn; tt++) {
    const int tb = tt & 1;
    const unsigned want = (unsigned)(tt + 1);
    uint4 s8[8];
    // ---- state slice for w1 (h or c quarter) ----
    {
      const int base = 16 * p + 8 * kb + (t & 1) * 32;
#pragma unroll
      for (int u = 0; u < 8; u++) s8[u] = stu[base + u];
    }
    __builtin_amdgcn_sched_barrier(0);
    // ---- w1 stream: hcp partial for (e, kq) ----
    {
      float a1 = 0.f;
#pragma unroll
      for (int c = 0; c < 8; c++) a1 = fd2x4u(ws[c * 1024], s8[c], a1);
      a1 += __shfl_xor(a1, 1, 64);
      if (!(t & 1)) hcp2[kb * 256 + e] = a1;
    }
    __syncthreads();  // MID: hcp2 ready
    if (wid == 0) {   // post hcp half-K sums
#pragma unroll
      for (int k = 0; k < 4; k++) {
        int i = 4 * l + k;
        float s = hcp2[i] + hcp2[256 + i];
        ast(&g_post1[g][tb][i], __builtin_bit_cast(unsigned, s));
      }
      asm volatile("s_waitcnt vmcnt(0)" ::: "memory");
      __builtin_amdgcn_sched_barrier(0);
      if (l == 0) ast(&g_f1[g], want);
    } else if (wid == 2) {  // fetch partner hcp (overlaps others' whh stream)
      while (ald(&g_f1[other]) < want) __builtin_amdgcn_s_sleep(2);
      asm volatile("" ::: "memory");
#pragma unroll
      for (int k = 0; k < 4; k++) {
        int i = 4 * l + k;
        hcp_in[i] = __builtin_bit_cast(float, ald(&g_post1[other][tb][i]));
      }
    }
    // ---- state slice for w_hh (h quarter) ----
    {
      const int base = 16 * p + 8 * kb;
#pragma unroll
      for (int u = 0; u < 8; u++) s8[u] = stu[base + u];
    }
    __builtin_amdgcn_sched_barrier(0);
    // ---- w_hh stream: gate partials for rows r and r+512 ----
    {
      float a0 = 0.f, a1 = 0.f;
#pragma unroll
      for (int c = 0; c < 8; c++) a0 = fd2x4u(ws[(8 + c) * 1024], s8[c], a0);
#pragma unroll
      for (int c = 0; c < 8; c++) a1 = fd2x4u(ws[(16 + c) * 1024], s8[c], a1);
      ag2[kb * 1024 + r] = a0;
      ag2[kb * 1024 + 512 + r] = a1;
    }
    __syncthreads();  // B1: ag2 complete
    if (wid <= 1) {   // post gate half-K sums (1024)
#pragma unroll
      for (int k = 0; k < 8; k++) {
        int i = 8 * t + k;
        float s = ag2[i] + ag2[1024 + i];
        ast(&g_post2[g][tb][i], __builtin_bit_cast(unsigned, s));
      }
      asm volatile("s_waitcnt vmcnt(0)" ::: "memory");
      __builtin_amdgcn_sched_barrier(0);
      if (l == 0) ast(&g_f2[wid][g], want);
    } else if (wid == 3 || wid == 4) {  // fetch partner gate partials
      const int j = wid - 3;
      while (ald(&g_f2[j][other]) < want) __builtin_amdgcn_s_sleep(2);
      asm volatile("" ::: "memory");
      const int i0 = (wid == 3) ? 8 * (t - 192) : 512 + 8 * (t - 256);
#pragma unroll
      for (int k = 0; k < 8; k++)
        gpar_in[i0 + k] = __builtin_bit_cast(float, ald(&g_post2[other][tb][i0 + k]));
    }
    // ---- P2: score partials (slice = wid, w = l) ----
    {
      float s_acc = 0.f;
#pragma unroll
      for (int i = 0; i < 2; i++) {
        int u = 2 * wid + i;
        uint4 ev = ep4u[u * 64 + l];
        unsigned em[4] = {ev.x, ev.y, ev.z, ev.w};
#pragma unroll
        for (int m = 0; m < 4; m++) {
          int e0 = 8 * u + 2 * m;
          h2 aa = __builtin_bit_cast(h2, em[m]);
          float hc0 = hcp2[e0] + hcp2[256 + e0] + hcp_in[e0];
          float hc1 = hcp2[e0 + 1] + hcp2[256 + e0 + 1] + hcp_in[e0 + 1];
          s_acc += w2_l[e0] * ftanh((float)aa.x + hc0);
          s_acc += w2_l[e0 + 1] * ftanh((float)aa.y + hc1);
        }
      }
      att_par[wid * 64 + l] = s_acc;
    }
    __syncthreads();  // B2: att_par + gpar_in ready
    if (wid < 4) {
      // ---- softmax + ytilde (redundant in waves 0..3) ----
      float sc = 0.f;
#pragma unroll
      for (int k = 0; k < 16; k++) sc += att_par[k * 64 + l];
      float m = sc;
#pragma unroll
      for (int dd = 32; dd; dd >>= 1) m = fmaxf(m, __shfl_xor(m, dd, 64));
      float pr = __builtin_exp2f((sc - m) * 1.4426950408889634f);
      float su = pr;
#pragma unroll
      for (int dd = 32; dd; dd >>= 1) su += __shfl_xor(su, dd, 64);
      attw = pr * __builtin_amdgcn_rcpf(su);
      float rx = attw * efc.x, ry = attw * efc.y, rz = attw * efc.z, rw = attw * efc.w;
#pragma unroll
      for (int dd = 32; dd; dd >>= 1) {
        rx += __shfl_xor(rx, dd, 64);
        ry += __shfl_xor(ry, dd, 64);
        rz += __shfl_xor(rz, dd, 64);
        rw += __shfl_xor(rw, dd, 64);
      }
      float4 yv = yh_l[tt];
      float4 yt4;
      yt4.x = rx + fcb_l[0] + fcy_l[0] * yv.x + fcy_l[1] * yv.y + fcy_l[2] * yv.z + fcy_l[3] * yv.w;
      yt4.y = ry + fcb_l[1] + fcy_l[4] * yv.x + fcy_l[5] * yv.y + fcy_l[6] * yv.z + fcy_l[7] * yv.w;
      yt4.z = rz + fcb_l[2] + fcy_l[8] * yv.x + fcy_l[9] * yv.y + fcy_l[10] * yv.z + fcy_l[11] * yv.w;
      yt4.w = rw + fcb_l[3] + fcy_l[12] * yv.x + fcy_l[13] * yv.y + fcy_l[14] * yv.z + fcy_l[15] * yv.w;
      // ---- finalize gates + LSTM (t<256) ----
      if (t < 256) {
        const int d = t;
        float gi = ag2[d] + ag2[1024 + d] + gpar_in[d] + bs4.x + dot4(wihl[d], yt4);
        float gf = ag2[256 + d] + ag2[1024 + 256 + d] + gpar_in[256 + d] + bs4.y + dot4(wihl[256 + d], yt4);
        float gg = ag2[512 + d] + ag2[1024 + 512 + d] + gpar_in[512 + d] + bs4.z + dot4(wihl[512 + d], yt4);
        float go = ag2[768 + d] + ag2[1024 + 768 + d] + gpar_in[768 + d] + bs4.w + dot4(wihl[768 + d], yt4);
        float iv = fsigm(gi), fv = fsigm(gf), Gv = ftanh(gg), ov = fsigm(go);
        c_reg = fv * c_reg + iv * Gv;
        float hn = ov * ftanh(c_reg);
        _Float16* sth = (_Float16*)st32;
        sth[d] = (_Float16)hn;
        sth[256 + d] = (_Float16)c_reg;
        hn_l[d] = hn;
      }
    }
    __syncthreads();  // B3: state updated
  }

  // ---- final: out[b,f] (p==0 only; single writer) ----
  if (p == 0 && t < 256) {
    const int f = wid;
    float v = 0.f;
#pragma unroll
    for (int m = 0; m < 4; m++) v += fcf_w[f * 512 + l + 64 * m] * hn_l[l + 64 * m];
    float4 fv = g_encfcf[b * 64 + l];
    v += attw * ((const float*)&fv)[f];
#pragma unroll
    for (int dd = 32; dd; dd >>= 1) v += __shfl_xor(v, dd, 64);
    if (l == 0) out[b * 4 + f] = v + fcf_b[f];
  }
}

extern "C" void kernel_launch(void* const* d_in, const int* in_sizes, int n_in,
                              void* d_out, int out_size, void* d_ws, size_t ws_size,
                              hipStream_t stream) {
  (void)in_sizes; (void)n_in; (void)d_ws; (void)ws_size; (void)out_size;
  const float* enc   = (const float*)d_in[0];
  const float* yhist = (const float*)d_in[1];
  const float* w1    = (const float*)d_in[2];
  const float* b1    = (const float*)d_in[3];
  const float* w2    = (const float*)d_in[4];
  // d_in[5] = attn_b2: softmax-invariant -> unused
  const float* w_ih  = (const float*)d_in[6];
  const float* w_hh  = (const float*)d_in[7];
  const float* b_ih  = (const float*)d_in[8];
  const float* b_hh  = (const float*)d_in[9];
  const float* fc_w  = (const float*)d_in[10];
  const float* fc_b  = (const float*)d_in[11];
  const float* fcf_w = (const float*)d_in[12];
  const float* fcf_b = (const float*)d_in[13];
  float* out = (float*)d_out;

  reset_kernel<<<dim3(1), dim3(256), 0, stream>>>();
  pack_kernel<<<dim3(192), dim3(256), 0, stream>>>(w1, w_hh);
  eproj_kernel<<<dim3(512), dim3(256), 0, stream>>>(enc, w1, b1);
  encfc_kernel<<<dim3(512), dim3(256), 0, stream>>>(enc, fc_w, fcf_w);
  decoder_kernel<<<dim3(256), dim3(1024), 0, stream>>>(yhist, w2, w_ih, b_ih, b_hh,
                                                       fc_w, fc_b, fcf_w, fcf_b, out);
}